// Round 8
// baseline (387.682 us; speedup 1.0000x reference)
//
#include <hip/hip_runtime.h>
#include <hip/hip_fp16.h>
#include <cstdint>
#include <cstddef>

typedef _Float16 f16x8 __attribute__((ext_vector_type(8)));
typedef _Float16 f16x4 __attribute__((ext_vector_type(4)));
typedef float    f32x4 __attribute__((ext_vector_type(4)));

#define GPTR(p) ((const __attribute__((address_space(1))) void*)(p))
#define SPTR(p) ((__attribute__((address_space(3))) void*)(p))

// ---------------------------------------------------------------------------
// Transpose + cast fp32 -> fp16 : W (R x C) row-major -> Wt (C x R) row-major
// (kept for fallback path)
// ---------------------------------------------------------------------------
__global__ void transpose_cast_kernel(const float* __restrict__ W,
                                      _Float16* __restrict__ Wt,
                                      int R, int C) {
  __shared__ float tile[32][33];
  const int c  = blockIdx.x * 32 + threadIdx.x;
  const int r0 = blockIdx.y * 32;
  for (int i = threadIdx.y; i < 32; i += 8)
    tile[i][threadIdx.x] = W[(size_t)(r0 + i) * C + c];
  __syncthreads();
  const int out_c = r0 + threadIdx.x;   // new col = old row
  const int oc0   = blockIdx.x * 32;    // new row = old col
  for (int i = threadIdx.y; i < 32; i += 8)
    Wt[(size_t)(oc0 + i) * R + out_c] = (_Float16)tile[threadIdx.x][i];
}

// ---------------------------------------------------------------------------
// Flat cast fp32 -> fp16, float4 granularity (fallback + split-V path)
// ---------------------------------------------------------------------------
__global__ void cast_f32_f16_kernel(const float* __restrict__ src,
                                    _Float16* __restrict__ dst) {
  const size_t i = (size_t)blockIdx.x * 256 + threadIdx.x;
  const float4 v = ((const float4*)src)[i];
  f16x4 h;
  h[0] = (_Float16)v.x; h[1] = (_Float16)v.y;
  h[2] = (_Float16)v.z; h[3] = (_Float16)v.w;
  ((f16x4*)dst)[i] = h;
}

// ---------------------------------------------------------------------------
// PREP (one launch, 36864 blocks x 256 thr):
//   blocks [0,2048)      : transpose+cast Wq (2048x1024) -> WqT (1024x2048)
//   blocks [2048,4096)   : transpose+cast Wk             -> WkT
//   blocks [4096,36864)  : cast Q|K fp32 -> fp16 into contiguous Qh|Kh
// ---------------------------------------------------------------------------
__global__ __launch_bounds__(256) void prep_kernel(
    const float* __restrict__ Wq, _Float16* __restrict__ WqT,
    const float* __restrict__ Wk, _Float16* __restrict__ WkT,
    const float* __restrict__ Q,  const float* __restrict__ K_,
    _Float16* __restrict__ QKh) {
  const int b = blockIdx.x;
  if (b < 4096) {
    const float* __restrict__ W  = (b < 2048) ? Wq : Wk;
    _Float16*    __restrict__ Wt = (b < 2048) ? WqT : WkT;
    const int bb = b & 2047;
    const int bx = bb & 31;        // C/32 = 1024/32 = 32
    const int by = bb >> 5;        // R/32 = 2048/32 = 64
    __shared__ float tile[32][33];
    const int tx = threadIdx.x & 31, ty = threadIdx.x >> 5;
    const int c = bx * 32 + tx, r0 = by * 32;
    for (int i = ty; i < 32; i += 8)
      tile[i][tx] = W[(size_t)(r0 + i) * 1024 + c];
    __syncthreads();
    const int out_c = r0 + tx, oc0 = bx * 32;
    for (int i = ty; i < 32; i += 8)
      Wt[(size_t)(oc0 + i) * 2048 + out_c] = (_Float16)tile[tx][i];
  } else {
    const int half4 = 8192 * 2048 / 4;             // 4194304
    const int i = (b - 4096) * 256 + (int)threadIdx.x;  // [0, 2*half4)
    const float4 v = (i < half4) ? ((const float4*)Q)[i]
                                 : ((const float4*)K_)[i - half4];
    f16x4 h;
    h[0] = (_Float16)v.x; h[1] = (_Float16)v.y;
    h[2] = (_Float16)v.z; h[3] = (_Float16)v.w;
    ((f16x4*)QKh)[i] = h;
  }
}

// ---------------------------------------------------------------------------
// MID (one launch):
//   blocks [0,2048)      : scale[row], one wave per row (4 rows/block)
//   blocks [2048,6144)   : transpose+cast Wv -> WvT (over WqT)
//   blocks [6144,22528)  : cast V -> Vh (only in merged-ws mode)
// ---------------------------------------------------------------------------
__global__ __launch_bounds__(256) void mid_kernel(
    const _Float16* __restrict__ QfH, const _Float16* __restrict__ KfH,
    float* __restrict__ scale,
    const float* __restrict__ Wv, _Float16* __restrict__ WvT,
    const float* __restrict__ V, _Float16* __restrict__ Vh) {
  const int b = blockIdx.x;
  if (b < 2048) {
    const int wv = threadIdx.x >> 6, lane = threadIdx.x & 63;
    const int row = b * 4 + wv;
    const _Float16* qrow = QfH + (size_t)row * 1024;
    const _Float16* krow = KfH + (size_t)row * 1024;
    const f16x8 q0 = ((const f16x8*)qrow)[lane * 2];
    const f16x8 q1 = ((const f16x8*)qrow)[lane * 2 + 1];
    const f16x8 k0 = ((const f16x8*)krow)[lane * 2];
    const f16x8 k1 = ((const f16x8*)krow)[lane * 2 + 1];
    float qk = 0.f, sq = 0.f, sk = 0.f;
#pragma unroll
    for (int i = 0; i < 8; ++i) {
      float q = (float)q0[i], k = (float)k0[i];
      qk += q * k; sq += q; sk += k;
      q = (float)q1[i]; k = (float)k1[i];
      qk += q * k; sq += q; sk += k;
    }
#pragma unroll
    for (int off = 32; off > 0; off >>= 1) {
      qk += __shfl_down(qk, off, 64);
      sq += __shfl_down(sq, off, 64);
      sk += __shfl_down(sk, off, 64);
    }
    if (lane == 0) scale[row] = qk / (sq * sk + 1e-6f);
  } else if (b < 6144) {
    const int bb = b - 2048;
    const int bx = bb & 63;        // 2048/32 = 64
    const int by = bb >> 6;
    __shared__ float tile[32][33];
    const int tx = threadIdx.x & 31, ty = threadIdx.x >> 5;
    const int c = bx * 32 + tx, r0 = by * 32;
    for (int i = ty; i < 32; i += 8)
      tile[i][tx] = Wv[(size_t)(r0 + i) * 2048 + c];
    __syncthreads();
    const int out_c = r0 + tx, oc0 = bx * 32;
    for (int i = ty; i < 32; i += 8)
      WvT[(size_t)(oc0 + i) * 2048 + out_c] = (_Float16)tile[tx][i];
  } else {
    const int i = (b - 6144) * 256 + (int)threadIdx.x;  // [0, 4194304)
    const float4 v = ((const float4*)V)[i];
    f16x4 h;
    h[0] = (_Float16)v.x; h[1] = (_Float16)v.y;
    h[2] = (_Float16)v.z; h[3] = (_Float16)v.w;
    ((f16x4*)Vh)[i] = h;
  }
}

// ---------------------------------------------------------------------------
// 256x256 deep-pipelined GEMM, 8 waves, BK=32, 3-tile prefetch ring.
// m201-faithful PHASE DISCIPLINE (round-7 kernel, resubmitted after infra
// failure -- barrier balance audited: uniform static barrier sequence per
// wave; vmcnt waits self-satisfying; no deadlock path).
// Each window = 2 phases, each phase = {ds_reads (4-8 b128); 2 gload_lds
// stage; [vmcnt]; BARRIER; s_waitcnt lgkmcnt(0); sched_barrier(0);
// setprio(1); 16 MFMA; setprio(0); BARRIER}. The lgkmcnt(0)+sched_barrier
// gate (rule #18) guarantees the 16-MFMA cluster issues with zero
// interleaved waits; the double barrier keeps waves in a clean
// {read/stage window}|{MFMA window} alternation (m196/m201: 62% MfmaUtil).
// Ring/vmcnt/swizzle unchanged:
//   - ring: 8 half-tile slots per operand (8 KiB each), 128 KiB LDS,
//     tiles t..t+3 resident, staging 3 tiles ahead, vmcnt(8) steady
//     (never drains mid-loop; 4/0 only in last windows).
//   - pair-swizzle LDS layout: 0 bank conflicts measured.
//   - bijective XCD swizzle: FETCH 49.6MB measured (~compulsory).
//   MODE 0: C = elu(acc + bias)           MODE 1: C = scale[row]*(acc + bias)
// ---------------------------------------------------------------------------
#define STG8(kk, h, slotv) do {                                                \
    __builtin_amdgcn_global_load_lds(GPTR(aRow + (h) * hstep + (kk)),          \
        SPTR(Aring + (slotv) * 4096 + wave * 512), 16, 0, 0);                  \
    __builtin_amdgcn_global_load_lds(GPTR(bRow + (h) * hstep + (kk)),          \
        SPTR(Bring + (slotv) * 4096 + wave * 512), 16, 0, 0);                  \
  } while (0)

#define WINDOW8(t_, DOSTG, DOWAIT, VCSTR) do {                                 \
    const int e_ = (2 * (t_)) & 7;                                             \
    const _Float16* Ab_ = Aring + ((e_ + wm) & 7) * 4096;                      \
    const _Float16* Bb_ = Bring + ((e_ + (wn >> 1)) & 7) * 4096                \
                          + (wn & 1) * 2048;                                   \
    f16x8 bf_[4], afL_[4], afH_[4];                                            \
    /* ---- phase 1: reads, stage-lo, barrier, lgkm-gate, MFMA-lo ---- */      \
    _Pragma("unroll")                                                          \
    for (int j_ = 0; j_ < 4; ++j_)                                             \
      bf_[j_] = *(const f16x8*)(Bb_ + j_ * 512 + lane_c * 8);                  \
    _Pragma("unroll")                                                          \
    for (int i_ = 0; i_ < 4; ++i_)                                             \
      afL_[i_] = *(const f16x8*)(Ab_ + i_ * 512 + lane_c * 8);                 \
    if (DOSTG) STG8(((t_) + 3) * 32, 0, (e_ + 6) & 7);                         \
    __builtin_amdgcn_s_barrier();                                              \
    asm volatile("s_waitcnt lgkmcnt(0)" ::: "memory");                         \
    __builtin_amdgcn_sched_barrier(0);                                         \
    __builtin_amdgcn_s_setprio(1);                                             \
    _Pragma("unroll")                                                          \
    for (int i_ = 0; i_ < 4; ++i_)                                             \
      _Pragma("unroll")                                                        \
      for (int j_ = 0; j_ < 4; ++j_)                                           \
        acc[i_][j_] = __builtin_amdgcn_mfma_f32_16x16x32_f16(afL_[i_], bf_[j_],\
                                                             acc[i_][j_],      \
                                                             0, 0, 0);         \
    __builtin_amdgcn_s_setprio(0);                                             \
    __builtin_amdgcn_s_barrier();                                              \
    /* ---- phase 2: reads, stage-hi, vmcnt, barrier, lgkm-gate, MFMA-hi */    \
    _Pragma("unroll")                                                          \
    for (int i_ = 0; i_ < 4; ++i_)                                             \
      afH_[i_] = *(const f16x8*)(Ab_ + (i_ + 4) * 512 + lane_c * 8);           \
    if (DOSTG) STG8(((t_) + 3) * 32, 1, (e_ + 7) & 7);                         \
    if (DOWAIT) asm volatile("s_waitcnt vmcnt(" VCSTR ")" ::: "memory");       \
    __builtin_amdgcn_s_barrier();                                              \
    asm volatile("s_waitcnt lgkmcnt(0)" ::: "memory");                         \
    __builtin_amdgcn_sched_barrier(0);                                         \
    __builtin_amdgcn_s_setprio(1);                                             \
    _Pragma("unroll")                                                          \
    for (int i_ = 0; i_ < 4; ++i_)                                             \
      _Pragma("unroll")                                                        \
      for (int j_ = 0; j_ < 4; ++j_)                                           \
        acc[i_ + 4][j_] = __builtin_amdgcn_mfma_f32_16x16x32_f16(afH_[i_],     \
                                                                 bf_[j_],      \
                                                                 acc[i_ + 4][j_],\
                                                                 0, 0, 0);     \
    __builtin_amdgcn_s_setprio(0);                                             \
    __builtin_amdgcn_s_barrier();                                              \
  } while (0)

template <int MODE, bool OUTHALF>
__global__ __launch_bounds__(512, 2) void gemm8p(
    const _Float16* __restrict__ A,
    const _Float16* __restrict__ Bt0, const _Float16* __restrict__ Bt1,
    const float* __restrict__ bias0, const float* __restrict__ bias1,
    int msplit, const float* __restrict__ scale,
    void* __restrict__ Cv, int K, int N) {
  // 8 half-tile slots per operand, 8 KiB (4096 halves) each: 128 KiB total.
  __shared__ __align__(16) _Float16 Aring[8 * 4096];
  __shared__ __align__(16) _Float16 Bring[8 * 4096];

  const int tid  = threadIdx.x;
  const int lane = tid & 63;
  const int wave = tid >> 6;       // 0..7
  const int quad = lane >> 4;
  const int r    = lane & 15;
  const int wm   = wave >> 2;      // 0..1  (M half)
  const int wn   = wave & 3;       // 0..3  (N quarter)

  // Bijective XCD-aware block swizzle (both grids: 256 blocks, %8 == 0).
  const int gx  = gridDim.x;
  const int nwg = gx * gridDim.y;
  int flat = blockIdx.y * gx + blockIdx.x;
  if ((nwg & 7) == 0) flat = (flat & 7) * (nwg >> 3) + (flat >> 3);
  const int m0 = (flat / gx) * 256;
  const int n0 = (flat % gx) * 256;

  const _Float16* Bt   = (m0 >= msplit) ? Bt1 : Bt0;
  const float*    bias = (m0 >= msplit) ? bias1 : bias0;

  // Per-thread staging source (pair-swizzle): 16B slot s = tid.
  const int sp  = tid >> 3;
  const int sub = (tid & 7) ^ (sp & 7);
  const int lr  = sp * 2 + (sub >> 2);   // local row in the 128-row half
  const int sc  = sub & 3;               // k-chunk (8 halves)
  const _Float16* aRow = A  + (size_t)(m0 + lr) * K + sc * 8;
  const _Float16* bRow = Bt + (size_t)(n0 + lr) * K + sc * 8;
  const int hstep = 128 * K;             // elements: half 0 -> half 1

  // Per-lane read constant: frag (lr=i*16+r, c=quad) lives at 16B slot
  // i*64 + lane_c, lane_c = (r>>1)*8 + ((((r&1)<<2)|quad) ^ (r>>1)).
  const int lane_c = (r >> 1) * 8 + (((((r & 1) << 2) | quad)) ^ (r >> 1));

  f32x4 acc[8][4] = {};
  const int NT = K >> 5;   // K/32 = 64 here (>= 4 required)

  // Prologue: stage tiles 0,1,2 (12 loads/thread, in order).
#pragma unroll
  for (int tt = 0; tt < 3; ++tt) {
    STG8(tt * 32, 0, (2 * tt) & 7);
    STG8(tt * 32, 1, (2 * tt + 1) & 7);
  }
  asm volatile("s_waitcnt vmcnt(8)" ::: "memory");   // tile 0 landed
  __builtin_amdgcn_s_barrier();
  asm volatile("" ::: "memory");

  for (int t = 0; t < NT - 3; ++t) WINDOW8(t, 1, 1, "8");
  WINDOW8(NT - 3, 0, 1, "4");
  WINDOW8(NT - 2, 0, 1, "0");
  WINDOW8(NT - 1, 0, 0, "0");

  // Epilogue: C/D layout col = lane&15, row = quad*4 + reg.
  float*    Cf = (float*)Cv;
  _Float16* Ch = (_Float16*)Cv;
#pragma unroll
  for (int i = 0; i < 8; ++i) {
    const int row0 = m0 + wm * 128 + i * 16 + quad * 4;
#pragma unroll
    for (int j = 0; j < 4; ++j) {
      const int col = n0 + wn * 64 + j * 16 + r;
      const float b = bias[col];
#pragma unroll
      for (int reg = 0; reg < 4; ++reg) {
        const int row = row0 + reg;
        float v = acc[i][j][reg] + b;
        if (MODE == 0) v = v > 0.f ? v : (expf(v) - 1.f);  // ELU (no +1)
        else           v = v * scale[row];
        if (OUTHALF) Ch[(size_t)row * N + col] = (_Float16)v;
        else         Cf[(size_t)row * N + col] = v;
      }
    }
  }
}

#undef STG8
#undef WINDOW8

// ---------------------------------------------------------------------------
// Legacy 128x128 GEMM kept for the small-workspace fallback path.
// ---------------------------------------------------------------------------
template <int MODE, bool AHALF, bool OUTHALF>
__global__ __launch_bounds__(256) void gemm2(
    const void* __restrict__ Av,
    const _Float16* __restrict__ Bt0, const _Float16* __restrict__ Bt1,
    const float* __restrict__ bias0, const float* __restrict__ bias1,
    int msplit, const float* __restrict__ scale,
    void* __restrict__ Cv, int K, int N) {
  constexpr int BK = 64;
  __shared__ __align__(16) _Float16 As[128 * BK];
  __shared__ __align__(16) _Float16 Bs[128 * BK];

  const int tid  = threadIdx.x;
  const int lane = tid & 63;
  const int wave = tid >> 6;
  const int quad = lane >> 4;
  const int r    = lane & 15;
  const int wm   = wave >> 1;
  const int wn   = wave & 1;
  const int m0   = blockIdx.y * 128;
  const int n0   = blockIdx.x * 128;

  const _Float16* Bt  = (m0 >= msplit) ? Bt1 : Bt0;
  const float* bias   = (m0 >= msplit) ? bias1 : bias0;

  size_t aoff[4], boff[4];
  int slot[4];
#pragma unroll
  for (int t = 0; t < 4; ++t) {
    const int s  = wave * 256 + t * 64 + lane;
    const int n  = s >> 3;
    const int kc = (s & 7) ^ (n & 7);
    aoff[t] = (size_t)(m0 + n) * K + kc * 8;
    boff[t] = (size_t)(n0 + n) * K + kc * 8;
    slot[t] = s;
  }

  f32x4 acc[4][4] = {};
  const _Float16* Ah = (const _Float16*)Av;
  const float*    Af = (const float*)Av;

  for (int k0 = 0; k0 < K; k0 += BK) {
    __syncthreads();
    if (AHALF) {
#pragma unroll
      for (int t = 0; t < 4; ++t)
        __builtin_amdgcn_global_load_lds(GPTR(Ah + aoff[t] + k0),
                                         SPTR(As + (wave * 256 + t * 64) * 8),
                                         16, 0, 0);
    } else {
#pragma unroll
      for (int t = 0; t < 4; ++t) {
        const float* ap = Af + aoff[t] + k0;
        const float4 v0 = *(const float4*)ap;
        const float4 v1 = *(const float4*)(ap + 4);
        f16x8 h;
        h[0] = (_Float16)v0.x; h[1] = (_Float16)v0.y;
        h[2] = (_Float16)v0.z; h[3] = (_Float16)v0.w;
        h[4] = (_Float16)v1.x; h[5] = (_Float16)v1.y;
        h[6] = (_Float16)v1.z; h[7] = (_Float16)v1.w;
        *(f16x8*)(As + (size_t)slot[t] * 8) = h;
      }
    }
#pragma unroll
    for (int t = 0; t < 4; ++t)
      __builtin_amdgcn_global_load_lds(GPTR(Bt + boff[t] + k0),
                                       SPTR(Bs + (wave * 256 + t * 64) * 8),
                                       16, 0, 0);
    __syncthreads();

#pragma unroll
    for (int ki = 0; ki < 2; ++ki) {
      f16x8 af[4], bf[4];
#pragma unroll
      for (int i = 0; i < 4; ++i) {
        const int an = wm * 64 + i * 16 + r;
        af[i] = *(const f16x8*)(As + (an * 8 + ((ki * 4 + quad) ^ (an & 7))) * 8);
      }
#pragma unroll
      for (int j = 0; j < 4; ++j) {
        const int bn = wn * 64 + j * 16 + r;
        bf[j] = *(const f16x8*)(Bs + (bn * 8 + ((ki * 4 + quad) ^ (bn & 7))) * 8);
      }
#pragma unroll
      for (int i = 0; i < 4; ++i)
#pragma unroll
        for (int j = 0; j < 4; ++j)
          acc[i][j] = __builtin_amdgcn_mfma_f32_16x16x32_f16(af[i], bf[j],
                                                             acc[i][j], 0, 0, 0);
    }
  }

  float*    Cf = (float*)Cv;
  _Float16* Ch = (_Float16*)Cv;
#pragma unroll
  for (int i = 0; i < 4; ++i) {
#pragma unroll
    for (int j = 0; j < 4; ++j) {
      const int col = n0 + wn * 64 + j * 16 + r;
      const float b = bias[col];
#pragma unroll
      for (int reg = 0; reg < 4; ++reg) {
        const int row = m0 + wm * 64 + i * 16 + quad * 4 + reg;
        float v = acc[i][j][reg] + b;
        if (MODE == 0) v = v > 0.f ? v : (expf(v) - 1.f);
        else           v = v * scale[row];
        if (OUTHALF) Ch[(size_t)row * N + col] = (_Float16)v;
        else         Cf[(size_t)row * N + col] = v;
      }
    }
  }
}

// ---------------------------------------------------------------------------
// scale[b] = (Qf[b].Kf[b]) / (sum(Qf[b]) * sum(Kf[b]) + eps), F = 1024.
// (fallback path only)
// ---------------------------------------------------------------------------
template <bool HALF>
__global__ void reduce_scale2(const void* __restrict__ Qf,
                              const void* __restrict__ Kf,
                              float* __restrict__ scale) {
  const int b = blockIdx.x;
  const int t = threadIdx.x;
  float q[4], k[4];
  if (HALF) {
    const f16x4 qh = ((const f16x4*)((const _Float16*)Qf + (size_t)b * 1024))[t];
    const f16x4 kh = ((const f16x4*)((const _Float16*)Kf + (size_t)b * 1024))[t];
#pragma unroll
    for (int i = 0; i < 4; ++i) { q[i] = (float)qh[i]; k[i] = (float)kh[i]; }
  } else {
    const float4 qv = ((const float4*)((const float*)Qf + (size_t)b * 1024))[t];
    const float4 kv = ((const float4*)((const float*)Kf + (size_t)b * 1024))[t];
    q[0] = qv.x; q[1] = qv.y; q[2] = qv.z; q[3] = qv.w;
    k[0] = kv.x; k[1] = kv.y; k[2] = kv.z; k[3] = kv.w;
  }
  float qk = q[0] * k[0] + q[1] * k[1] + q[2] * k[2] + q[3] * k[3];
  float sq = q[0] + q[1] + q[2] + q[3];
  float sk = k[0] + k[1] + k[2] + k[3];
#pragma unroll
  for (int off = 32; off > 0; off >>= 1) {
    qk += __shfl_down(qk, off, 64);
    sq += __shfl_down(sq, off, 64);
    sk += __shfl_down(sk, off, 64);
  }
  __shared__ float buf[3][4];
  const int lane = t & 63, wv = t >> 6;
  if (lane == 0) { buf[0][wv] = qk; buf[1][wv] = sq; buf[2][wv] = sk; }
  __syncthreads();
  if (t == 0) {
    const float QK = buf[0][0] + buf[0][1] + buf[0][2] + buf[0][3];
    const float SQ = buf[1][0] + buf[1][1] + buf[1][2] + buf[1][3];
    const float SK = buf[2][0] + buf[2][1] + buf[2][2] + buf[2][3];
    scale[b] = QK / (SQ * SK + 1e-6f);
  }
}

// ---------------------------------------------------------------------------
extern "C" void kernel_launch(void* const* d_in, const int* in_sizes, int n_in,
                              void* d_out, int out_size, void* d_ws,
                              size_t ws_size, hipStream_t stream) {
  const float* Q  = (const float*)d_in[0];
  const float* K_ = (const float*)d_in[1];
  const float* V  = (const float*)d_in[2];
  const float* Wq = (const float*)d_in[3];
  const float* bq = (const float*)d_in[4];
  const float* Wk = (const float*)d_in[5];
  const float* bk = (const float*)d_in[6];
  const float* Wv = (const float*)d_in[7];
  const float* bv = (const float*)d_in[8];
  float* out = (float*)d_out;

  const int B = 8192, D = 2048, F = 1024;
  const size_t MiB = 1u << 20;
  char* ws = (char*)d_ws;

  // Fast path ws layout:
  //   [0, 8M):      WqT(4M)+WkT(4M); WvT(8M) overwrites after feat GEMM
  //   [8M, 40M):    QfH(16M)+KfH(16M) contiguous
  //   [40M, +32K):  scale
  //   [41M, 73M):   Vh  (ONLY if ws >= 73M; else Vh reuses [8M,24M) via a
  //                 separate cast launch AFTER mid_kernel's reduce)
  const size_t NEED_FAST  = 40 * MiB + 64 * 1024;
  const size_t NEED_FAST2 = 73 * MiB;

  if (ws_size >= NEED_FAST) {
    _Float16* WqT = (_Float16*)ws;
    _Float16* WkT = (_Float16*)(ws + 4 * MiB);
    _Float16* WvT = (_Float16*)ws;             // reuses weight region
    _Float16* QfH = (_Float16*)(ws + 8 * MiB);
    _Float16* KfH = (_Float16*)(ws + 24 * MiB);
    float* scale  = (float*)(ws + 40 * MiB);
    const bool merged = (ws_size >= NEED_FAST2);
    _Float16* Vh = merged ? (_Float16*)(ws + 41 * MiB)
                          : (_Float16*)(ws + 8 * MiB);  // over QfH (post-reduce)
    _Float16* Qh = (_Float16*)d_out;                  // d_out as fp16 scratch
    _Float16* Kh = (_Float16*)d_out + (size_t)B * D;  // adjacent -> stacked M
    (void)Kh;

    // 1) prep: WqT + WkT transpose, Q|K cast   (2048+2048+32768 blocks)
    prep_kernel<<<36864, 256, 0, stream>>>(Wq, WqT, Wk, WkT, Q, K_, Qh);

    // 2) stacked feature GEMM: M = 16384 ([Qh;Kh]), msplit 8192 selects
    //    Wq/bq vs Wk/bk. Grid 4x64 = 256 blocks, 512 thr, 128 KiB LDS.
    gemm8p<0, true><<<dim3(F / 256, (2 * B) / 256), 512, 0, stream>>>(
        Qh, WqT, WkT, bq, bk, B, nullptr, QfH, D, F);

    // 3) mid: reduce(scale) + WvT transpose (+ V cast when merged).
    if (merged) {
      mid_kernel<<<22528, 256, 0, stream>>>(QfH, KfH, scale, Wv, WvT, V, Vh);
    } else {
      mid_kernel<<<6144, 256, 0, stream>>>(QfH, KfH, scale, Wv, WvT, V, Vh);
      cast_f32_f16_kernel<<<(B * D / 4) / 256, 256, 0, stream>>>(V, Vh);
    }

    // 4) V-projection GEMM with fused scale.
    gemm8p<1, false><<<dim3(D / 256, B / 256), 512, 0, stream>>>(
        Vh, WvT, WvT, bv, bv, 1 << 30, scale, out, D, D);
  } else {
    // Fallback: fp32 A staging in-kernel, Qf/Kf fp32 in d_out.
    _Float16* WqT = (_Float16*)ws;
    _Float16* WkT = (_Float16*)(ws + 4 * MiB);
    _Float16* WvT = (_Float16*)(ws + 8 * MiB);
    float* scale  = (float*)(ws + 16 * MiB);
    float* Qf = out;
    float* Kf = out + (size_t)B * F;

    dim3 tb(32, 8);
    transpose_cast_kernel<<<dim3(F / 32, D / 32), tb, 0, stream>>>(Wq, WqT, D, F);
    transpose_cast_kernel<<<dim3(F / 32, D / 32), tb, 0, stream>>>(Wk, WkT, D, F);
    transpose_cast_kernel<<<dim3(D / 32, D / 32), tb, 0, stream>>>(Wv, WvT, D, D);

    gemm2<0, false, false><<<dim3(F / 128, B / 128), 256, 0, stream>>>(
        Q, WqT, WqT, bq, bq, 1 << 30, nullptr, Qf, D, F);
    gemm2<0, false, false><<<dim3(F / 128, B / 128), 256, 0, stream>>>(
        K_, WkT, WkT, bk, bk, 1 << 30, nullptr, Kf, D, F);
    reduce_scale2<false><<<B, 256, 0, stream>>>(Qf, Kf, scale);
    gemm2<1, false, false><<<dim3(D / 128, B / 128), 256, 0, stream>>>(
        V, WvT, WvT, bv, bv, 1 << 30, scale, out, D, D);
  }
}